// Round 8
// baseline (1310.797 us; speedup 1.0000x reference)
//
#include <hip/hip_runtime.h>
#include <math.h>

// SoftSkeletonize via the erosion-chain identity:
//   e_0 = img, e_{i+1} = erode(e_i)      (erode = 5-pt cross min, +inf pad)
//   delta_i = relu(e_i - dilate3x3(e_{i+1}))            (dilate pad = -inf)
//   skel: s = delta_0; s += relu(delta_i - s*delta_i), i = 1..40
//
// 5 fused phases (S = 9,8,8,8,8). Per 64x64 tile, stage e + halo in LDS,
// S+1 merged passes (pass t: erode e_{t-1}->e_t; delta_{t-2} from
// dilate(e_{t-1}); e_{t-2} from a prev1/prev2 register rotation).
//
// Round-8 changes vs r7 (kernel is LDS-pipe-bound: ~198 of 227 us/phase):
//  - Horizontal edge scalars via paired b32 loads (sb[o-1], sb[o+4] ->
//    ds_read2_b32): replaces 4 shifted b128 reads per thread-pass with 2
//    read2 ops in erode (and 4->2 in the dilate path). ~33% fewer LDS
//    cycles in the erode hot path.
//  - Per-pass region shrink: pass t only needs e_t valid on rows
//    [10-(S-t), 75+(S-t)] x cols [11-(S-t), 76+(S-t)]; outside cells go
//    stale, never consumed (consumers at t+1 read exactly one cell inward).
//  - Keep r7's 2-round x 2-row structure, NT=512, STRD=96 (r6 showed the
//    1-round/4-row shape collapses ILP/occupancy).

#define HH 1024
#define WW 1024
#define T 64
#define MTR 11                 // top row margin (central rows = buf rows 11..74)
#define MTC 12                 // left col margin (central quads 3..18)
#define RH 86                  // buffer rows
#define STq 24                 // quads per row (multiple of 8)
#define STRD 96                // floats per row
#define NT 512
#define PADF 4

#define LD4(p)    (*(const float4*)(p))
#define ST4(p, v) (*(float4*)(p) = (v))

__device__ __forceinline__ float relu_(float x) { return x > 0.f ? x : 0.f; }
__device__ __forceinline__ float4 min4_(float4 a, float4 b) {
    return make_float4(fminf(a.x,b.x), fminf(a.y,b.y), fminf(a.z,b.z), fminf(a.w,b.w));
}
__device__ __forceinline__ float4 max4_(float4 a, float4 b) {
    return make_float4(fmaxf(a.x,b.x), fmaxf(a.y,b.y), fmaxf(a.z,b.z), fmaxf(a.w,b.w));
}
__device__ __forceinline__ float4 hmin4(float L, float4 a, float R) {
    float4 h;
    h.x = fminf(L,   fminf(a.x, a.y)); h.y = fminf(a.x, fminf(a.y, a.z));
    h.z = fminf(a.y, fminf(a.z, a.w)); h.w = fminf(a.z, fminf(a.w, R));
    return h;
}
__device__ __forceinline__ float4 hmax4(float L, float4 a, float R) {
    float4 h;
    h.x = fmaxf(L,   fmaxf(a.x, a.y)); h.y = fmaxf(a.x, fmaxf(a.y, a.z));
    h.z = fmaxf(a.y, fmaxf(a.z, a.w)); h.w = fmaxf(a.z, fmaxf(a.w, R));
    return h;
}
__device__ __forceinline__ float4 dmask4(float4 v, float rm, float4 cm) {
    float4 o;
    o.x = fminf(fminf(v.x, cm.x), rm); o.y = fminf(fminf(v.y, cm.y), rm);
    o.z = fminf(fminf(v.z, cm.z), rm); o.w = fminf(fminf(v.w, cm.w), rm);
    return o;
}
__device__ __forceinline__ void skup(float4& s, float4 e, float4 d, bool init) {
    float4 dl;
    dl.x = relu_(e.x - d.x); dl.y = relu_(e.y - d.y);
    dl.z = relu_(e.z - d.z); dl.w = relu_(e.w - d.w);
    if (init) { s = dl; }
    else {
        s.x += relu_(dl.x - s.x * dl.x); s.y += relu_(dl.y - s.y * dl.y);
        s.z += relu_(dl.z - s.z * dl.z); s.w += relu_(dl.w - s.w * dl.w);
    }
}

__global__ __launch_bounds__(NT, 4) void phase_kernel(
    const float* __restrict__ src, float* __restrict__ dst,
    float* __restrict__ skel, int S, int first, int last)
{
    __shared__ __align__(16) float b0_[PADF + RH * STRD + PADF];
    __shared__ __align__(16) float b1_[PADF + RH * STRD + PADF];
    float* buf0 = b0_ + PADF;
    float* buf1 = b1_ + PADF;

    const int h0 = blockIdx.y * T;
    const int w0 = blockIdx.x * T;
    const size_t plane = (size_t)HH * WW;
    const float* sp = src + blockIdx.z * plane;
    float* skp = skel + blockIdx.z * plane;
    float* dp = dst ? dst + blockIdx.z * plane : nullptr;

    const int tid = threadIdx.x;
    const bool border = (h0 == 0) || (w0 == 0) || (h0 + T == HH) || (w0 + T == WW);

    // ---- stage e_{i0} (+inf outside image) into buf0
    if (!border) {
        const float* base = sp + (size_t)(h0 - MTR) * WW + (w0 - MTC);
        for (int i = tid; i < RH * STq; i += NT) {
            int r = i / STq, q = i - r * STq;
            ST4(&buf0[r * STRD + 4 * q], LD4(base + (size_t)r * WW + 4 * q));
        }
    } else {
        for (int i = tid; i < RH * STRD; i += NT) {
            int r = i / STRD, c = i - r * STRD;
            int gh = h0 - MTR + r, gw = w0 - MTC + c;
            float v = INFINITY;
            if ((unsigned)gh < HH && (unsigned)gw < WW) v = sp[(size_t)gh * WW + gw];
            buf0[r * STRD + c] = v;
        }
    }

    // ---- geometry: 2-row patches; round q handles idx = tid + NT*q
    int pq[2], cq[2], oq[2];
    bool act[2], cen[2];
    float4 s0[2], s1[2];
    float4 p1a[2], p1b[2], p2a[2], p2b[2];   // e_{t-1}, e_{t-2} at own quads
#pragma unroll
    for (int q = 0; q < 2; ++q) {
        int idx = tid + NT * q;
        int p = idx / STq, c = idx - STq * p;
        pq[q] = p; cq[q] = c;
        act[q] = (p < 42) && (c < 22);
        oq[q] = (1 + 2 * p) * STRD + 4 * c;
        cen[q] = act[q] && (p >= 5) && (p <= 36) && (c >= 3) && (c <= 18);
    }
    if (!first) {
#pragma unroll
        for (int q = 0; q < 2; ++q) if (cen[q]) {
            const float* g = skp + (size_t)(h0 + 2 * pq[q] - 10) * WW + (w0 + 4 * cq[q] - 12);
            s0[q] = LD4(g); s1[q] = LD4(g + WW);
        }
    }
    __syncthreads();

    // prev1 = e_0 at own quads (staged values)
#pragma unroll
    for (int q = 0; q < 2; ++q) if (cen[q]) {
        p1a[q] = LD4(buf0 + oq[q]);
        p1b[q] = LD4(buf0 + oq[q] + STRD);
    }

    for (int t = 1; t <= S + 1; ++t) {
        float* sb = ((t - 1) & 1) ? buf1 : buf0;
        float* db = (t & 1) ? buf1 : buf0;
        const bool do_er = (t <= S);
        const bool do_dl = (t >= 2);
        const bool init = (first != 0) && (t == 2);
        // per-pass needed region (buffer coords); outside = stale, unconsumed
        const int rem = do_er ? (S - t) : 0;
        int rlo = 10 - rem; if (rlo < 1) rlo = 1;
        int rhi = 75 + rem; if (rhi > 84) rhi = 84;
        int clo = 11 - rem; if (clo < 0) clo = 0;
        int chi = 76 + rem; if (chi > 87) chi = 87;
#pragma unroll
        for (int q = 0; q < 2; ++q) {
            if (!act[q]) continue;
            const int r0 = 1 + 2 * pq[q];
            const int f0 = 4 * cq[q];
            const bool shr = (r0 + 1 >= rlo) && (r0 <= rhi) && (f0 + 3 >= clo) && (f0 <= chi);
            const bool er = do_er && shr;
            const bool cw = cen[q] && do_dl;
            if (!(er || cw)) continue;
            const int o = oq[q];
            // unshifted quad reads (b128, conflict-free)
            float4 U   = LD4(sb + o - STRD);
            float4 A0  = LD4(sb + o);
            float4 A1  = LD4(sb + o + STRD);
            float4 D   = LD4(sb + o + 2 * STRD);
            // edge scalars as paired b32 (-> ds_read2_b32)
            float L0 = sb[o - 1],        R0 = sb[o + 4];
            float L1 = sb[o + STRD - 1], R1 = sb[o + STRD + 4];
            float eUm, eUp, eDm, eDp;
            if (cw) {
                eUm = sb[o - STRD - 1];     eUp = sb[o - STRD + 4];
                eDm = sb[o + 2 * STRD - 1]; eDp = sb[o + 2 * STRD + 4];
            }
            float4 e0, e1;
            if (er) {
                e0 = min4_(min4_(U,  A1), hmin4(L0, A0, R0));
                e1 = min4_(min4_(A0, D),  hmin4(L1, A1, R1));
                if (border) {   // force +inf at out-of-image outputs
                    int ghb = h0 - MTR + r0;
                    int gwb = w0 - MTC + f0;
                    float4 cwm;
                    cwm.x = (unsigned)(gwb + 0) < WW ? -INFINITY : INFINITY;
                    cwm.y = (unsigned)(gwb + 1) < WW ? -INFINITY : INFINITY;
                    cwm.z = (unsigned)(gwb + 2) < WW ? -INFINITY : INFINITY;
                    cwm.w = (unsigned)(gwb + 3) < WW ? -INFINITY : INFINITY;
                    float r0m = (unsigned)ghb       < HH ? -INFINITY : INFINITY;
                    float r1m = (unsigned)(ghb + 1) < HH ? -INFINITY : INFINITY;
                    e0 = max4_(e0, max4_(make_float4(r0m, r0m, r0m, r0m), cwm));
                    e1 = max4_(e1, max4_(make_float4(r1m, r1m, r1m, r1m), cwm));
                }
                ST4(db + o, e0);
                ST4(db + o + STRD, e1);
            }
            if (cw) {
                float4 tU = U, tA = A0, tB = A1, tD = D;
                float lU = eUm, rU = eUp, lA = L0, rA = R0;
                float lB = L1, rB = R1, lD = eDm, rD = eDp;
                if (border) {   // mask inputs to -inf outside image
                    int ghb = h0 - MTR + r0;
                    int gwb = w0 - MTC + f0;
                    float rm0 = (unsigned)(ghb - 1) < HH ? INFINITY : -INFINITY;
                    float rm1 = (unsigned)(ghb)     < HH ? INFINITY : -INFINITY;
                    float rm2 = (unsigned)(ghb + 1) < HH ? INFINITY : -INFINITY;
                    float rm3 = (unsigned)(ghb + 2) < HH ? INFINITY : -INFINITY;
                    float cmL = (unsigned)(gwb - 1) < WW ? INFINITY : -INFINITY;
                    float cmR = (unsigned)(gwb + 4) < WW ? INFINITY : -INFINITY;
                    float4 cmC;
                    cmC.x = (unsigned)(gwb + 0) < WW ? INFINITY : -INFINITY;
                    cmC.y = (unsigned)(gwb + 1) < WW ? INFINITY : -INFINITY;
                    cmC.z = (unsigned)(gwb + 2) < WW ? INFINITY : -INFINITY;
                    cmC.w = (unsigned)(gwb + 3) < WW ? INFINITY : -INFINITY;
                    tU = dmask4(tU, rm0, cmC); tA = dmask4(tA, rm1, cmC);
                    tB = dmask4(tB, rm2, cmC); tD = dmask4(tD, rm3, cmC);
                    lU = fminf(fminf(lU, cmL), rm0); rU = fminf(fminf(rU, cmR), rm0);
                    lA = fminf(fminf(lA, cmL), rm1); rA = fminf(fminf(rA, cmR), rm1);
                    lB = fminf(fminf(lB, cmL), rm2); rB = fminf(fminf(rB, cmR), rm2);
                    lD = fminf(fminf(lD, cmL), rm3); rD = fminf(fminf(rD, cmR), rm3);
                }
                float4 hU = hmax4(lU, tU, rU);
                float4 hA = hmax4(lA, tA, rA);
                float4 hB = hmax4(lB, tB, rB);
                float4 hD = hmax4(lD, tD, rD);
                float4 d0 = max4_(hU, max4_(hA, hB));
                float4 d1 = max4_(hA, max4_(hB, hD));
                skup(s0[q], p2a[q], d0, init);
                skup(s1[q], p2b[q], d1, init);
            }
            if (cen[q] && er) {   // rotate register chain
                p2a[q] = p1a[q]; p1a[q] = e0;
                p2b[q] = p1b[q]; p1b[q] = e1;
            }
        }
        __syncthreads();
    }

    // ---- writeback: skel always; e_S (= prev1 regs) if not last phase
#pragma unroll
    for (int q = 0; q < 2; ++q) if (cen[q]) {
        size_t grow = (size_t)(h0 + 2 * pq[q] - 10) * WW + (w0 + 4 * cq[q] - 12);
        ST4(skp + grow, s0[q]);
        ST4(skp + grow + WW, s1[q]);
        if (!last) {
            ST4(dp + grow, p1a[q]);
            ST4(dp + grow + WW, p1b[q]);
        }
    }
}

extern "C" void kernel_launch(void* const* d_in, const int* in_sizes, int n_in,
                              void* d_out, int out_size, void* d_ws, size_t ws_size,
                              hipStream_t stream) {
    const float* img = (const float*)d_in[0];
    float* skel = (float*)d_out;
    const int B = in_sizes[0] / (HH * WW);  // 16
    const size_t plane = (size_t)HH * WW;

    float* e0 = (float*)d_ws;
    float* e1 = e0 + (size_t)B * plane;

    dim3 grid(WW / T, HH / T, B);
    dim3 block(NT);

    const int Ks[5] = {9, 8, 8, 8, 8};   // 41 deltas total (init + 40 iters)
    const float* src = img;
    float* ebufs[2] = {e0, e1};
    for (int p = 0; p < 5; ++p) {
        int first = (p == 0), last = (p == 4);
        float* dstp = last ? nullptr : ebufs[p & 1];
        phase_kernel<<<grid, block, 0, stream>>>(src, dstp, skel, Ks[p], first, last);
        src = dstp;
    }
}